// Round 1
// baseline (228.201 us; speedup 1.0000x reference)
//
#include <hip/hip_runtime.h>

// KeyValueMemoryNetwork: B=16, S=2048, C=16, D=256, V=100000
// One wave per token (b,s). Lane l owns D-elements [4l, 4l+4).
// Embeddings for all C=16 slots live in registers (16 x float4 = 64 VGPRs).

#define KV_C 16
#define KV_D 256
#define KV_TOKENS (16 * 2048)

__global__ __launch_bounds__(256) void kv_mem_kernel(
    const int* __restrict__ seq,      // [TOKENS, C] int32
    const float* __restrict__ hidden, // [TOKENS, D]
    const float* __restrict__ table,  // [V, D]
    float* __restrict__ out)          // [TOKENS, D]
{
    const int wave = threadIdx.x >> 6;
    const int lane = threadIdx.x & 63;
    const int token = blockIdx.x * 4 + wave;

    // hidden chunk for this lane
    const float4 h = *(const float4*)(hidden + (size_t)token * KV_D + lane * 4);

    // each of lanes 0..15 loads one index, broadcast via shuffle
    const int* sp = seq + (size_t)token * KV_C;
    int myidx = (lane < KV_C) ? sp[lane] : 0;

    float4 e[KV_C];
    float  u[KV_C];

    #pragma unroll
    for (int c = 0; c < KV_C; ++c) {
        int idx = __shfl(myidx, c);      // wave-uniform
        float4 ev = make_float4(0.f, 0.f, 0.f, 0.f);
        if (idx != 0) {                   // padding_idx=0 -> zero row; uniform branch
            ev = *(const float4*)(table + (size_t)idx * KV_D + lane * 4);
        }
        e[c] = ev;
        u[c] = h.x * ev.x + h.y * ev.y + h.z * ev.z + h.w * ev.w;
    }

    // butterfly reduce all 16 scores across the 64-lane wave
    #pragma unroll
    for (int s = 32; s >= 1; s >>= 1) {
        #pragma unroll
        for (int c = 0; c < KV_C; ++c) {
            u[c] += __shfl_xor(u[c], s);
        }
    }

    // softmax over C (wave-uniform, computed redundantly per lane)
    float m = u[0];
    #pragma unroll
    for (int c = 1; c < KV_C; ++c) m = fmaxf(m, u[c]);
    float sum = 0.f;
    #pragma unroll
    for (int c = 0; c < KV_C; ++c) {
        u[c] = __expf(u[c] - m);          // reuse u[] as p[]
        sum += u[c];
    }
    const float inv = 1.0f / sum;

    // weighted combine: o[d] = sum_c p[c] * e[c][d]
    float4 o = make_float4(0.f, 0.f, 0.f, 0.f);
    #pragma unroll
    for (int c = 0; c < KV_C; ++c) {
        const float w = u[c] * inv;
        o.x += w * e[c].x;
        o.y += w * e[c].y;
        o.z += w * e[c].z;
        o.w += w * e[c].w;
    }

    *(float4*)(out + (size_t)token * KV_D + lane * 4) = o;
}

extern "C" void kernel_launch(void* const* d_in, const int* in_sizes, int n_in,
                              void* d_out, int out_size, void* d_ws, size_t ws_size,
                              hipStream_t stream) {
    const int*   seq    = (const int*)d_in[0];
    const float* hidden = (const float*)d_in[1];
    const float* table  = (const float*)d_in[2];
    float*       out    = (float*)d_out;

    dim3 grid(KV_TOKENS / 4);   // 8192 blocks, 4 waves (tokens) per block
    dim3 block(256);
    kv_mem_kernel<<<grid, block, 0, stream>>>(seq, hidden, table, out);
}